// Round 1
// baseline (19.815 us; speedup 1.0000x reference)
//
#include <hip/hip_runtime.h>

// SubTB loss, T=8192, LAMBDA=0.9.
// total = sum_{i<j} lam^(j-i) (d[i]-d[j])^2, d = lfr + cumsum(log_pbs - log_pfs)
// wsum  = sum_{i<j} lam^(j-i)  (data-independent, host-computed exactly)
// out   = total / wsum.
// Weights beyond distance K=512 are < 4e-24 -> truncate (error ~1e-10 << 0.43 threshold).

#define TT 8192
#define NTH 1024
#define KMAX 512
#define LAMBDA 0.9

// ---------------- Kernel A: prefix scan -> d[0..T] (double) ----------------
__global__ __launch_bounds__(NTH) void compute_d_kernel(
    const float* __restrict__ log_pfs,
    const float* __restrict__ log_pbs,
    const float* __restrict__ log_flows,
    const float* __restrict__ log_reward,
    double* __restrict__ d) {
  __shared__ double sdata[NTH];
  const int tid = threadIdx.x;
  const int base = tid * 8;  // 1024 threads x 8 elems = 8192

  double e[8], lexcl[8];
  double run = 0.0;
#pragma unroll
  for (int r = 0; r < 8; ++r) {
    e[r] = (double)log_pbs[base + r] - (double)log_pfs[base + r];
    lexcl[r] = run;
    run += e[r];
  }
  sdata[tid] = run;
  __syncthreads();
  // Hillis-Steele inclusive scan over 1024 thread-totals
  for (int off = 1; off < NTH; off <<= 1) {
    double v = sdata[tid];
    double u = (tid >= off) ? sdata[tid - off] : 0.0;
    __syncthreads();
    sdata[tid] = v + u;
    __syncthreads();
  }
  const double excl = (tid > 0) ? sdata[tid - 1] : 0.0;
#pragma unroll
  for (int r = 0; r < 8; ++r) {
    d[base + r] = (double)log_flows[base + r] + excl + lexcl[r];
  }
  if (tid == NTH - 1) {
    // terminal flow replaced by log_reward; prefix = total sum
    d[TT] = (double)log_reward[0] + sdata[NTH - 1];
  }
}

// ---------------- Kernel B: per-j truncated pair sum ----------------
// block j (1 wave, 64 lanes): partial[j] = sum_{k=1..min(j,KMAX)} lam^k (d[j-k]-d[j])^2
__global__ __launch_bounds__(64) void pair_sum_kernel(
    const double* __restrict__ d,
    double* __restrict__ partial) {
  const int j = blockIdx.x;
  const int t = threadIdx.x;
  const double dj = d[j];
  const int kmax = (j < KMAX) ? j : KMAX;

  // lane t handles k = t+1, t+65, t+129, ...
  double w = pow((double)LAMBDA, (double)(t + 1));
  const double step = pow((double)LAMBDA, 64.0);  // lam^64
  double acc = 0.0;
  for (int k = t + 1; k <= kmax; k += 64) {
    const double b = d[j - k] - dj;
    acc += w * b * b;
    w *= step;
  }
  // wave-64 shuffle reduction (deterministic)
#pragma unroll
  for (int off = 32; off > 0; off >>= 1) {
    acc += __shfl_down(acc, off, 64);
  }
  if (t == 0) partial[j] = acc;
}

// ---------------- Kernel C: final reduce + divide ----------------
__global__ __launch_bounds__(NTH) void final_reduce_kernel(
    const double* __restrict__ partial,
    float* __restrict__ out,
    double wsum) {
  __shared__ double sdata[NTH];
  const int tid = threadIdx.x;
  double acc = 0.0;
  for (int i = tid; i <= TT; i += NTH) acc += partial[i];
  sdata[tid] = acc;
  __syncthreads();
  for (int off = NTH / 2; off > 0; off >>= 1) {
    if (tid < off) sdata[tid] += sdata[tid + off];
    __syncthreads();
  }
  if (tid == 0) out[0] = (float)(sdata[0] / wsum);
}

extern "C" void kernel_launch(void* const* d_in, const int* in_sizes, int n_in,
                              void* d_out, int out_size, void* d_ws, size_t ws_size,
                              hipStream_t stream) {
  const float* log_pfs    = (const float*)d_in[0];
  const float* log_pbs    = (const float*)d_in[1];
  const float* log_flows  = (const float*)d_in[2];
  const float* log_reward = (const float*)d_in[3];
  float* out = (float*)d_out;

  double* d_arr   = (double*)d_ws;              // 8193 doubles
  double* partial = d_arr + (TT + 1);           // 8193 doubles

  // Exact wsum on host (deterministic, data-independent): sum_{k=1..T} (T+1-k) lam^k
  double wsum = 0.0, lp = 1.0;
  for (int k = 1; k <= TT; ++k) {
    lp *= LAMBDA;
    wsum += (double)(TT + 1 - k) * lp;
  }

  compute_d_kernel<<<1, NTH, 0, stream>>>(log_pfs, log_pbs, log_flows, log_reward, d_arr);
  pair_sum_kernel<<<TT + 1, 64, 0, stream>>>(d_arr, partial);
  final_reduce_kernel<<<1, NTH, 0, stream>>>(partial, out, wsum);
}

// Round 2
// 12.560 us; speedup vs baseline: 1.5776x; 1.5776x over previous
//
#include <hip/hip_runtime.h>

// SubTB loss, T=8192, LAMBDA=0.9 — single fused kernel, O(T) exact.
// d_j = lfr_j + sum_{i<j} e_i,  e = log_pbs - log_pfs
// total = sum_{i<j} lam^{j-i} (d_i-d_j)^2
//       = [lam/(1-lam)] * sum_i d_i^2 (2 - lam^i - lam^{T-i})  -  2 * sum_j d_j c_j
//   where c_j = sum_{i<j} lam^{j-i} d_i  (linear recurrence c_{j+1} = lam*(c_j + d_j))
// wsum is data-independent, computed exactly on host.

#define TT 8192
#define NTH 1024
#define LAM 0.9

__global__ __launch_bounds__(NTH) void subtb_fused_kernel(
    const float* __restrict__ log_pfs,
    const float* __restrict__ log_pbs,
    const float* __restrict__ log_flows,
    const float* __restrict__ log_reward,
    float* __restrict__ out, double wsum) {
  const int tid  = threadIdx.x;
  const int lane = tid & 63;
  const int wid  = tid >> 6;
  const int base = tid * 8;  // 1024 threads x 8 elems = 8192 (idx 8192 handled by last thread)

  __shared__ double wtot1[16];        // plain-scan wave totals
  __shared__ double wtot2[16];        // weighted-scan wave totals
  __shared__ double rt1[16], rt2[16]; // final reduction

  // ---- vectorized loads: 8 consecutive f32 per array ----
  const float4* pf4 = (const float4*)(log_pfs + base);
  const float4* pb4 = (const float4*)(log_pbs + base);
  const float4* fl4 = (const float4*)(log_flows + base);
  float4 a0 = pf4[0], a1 = pf4[1];
  float4 b0 = pb4[0], b1 = pb4[1];
  float4 f0 = fl4[0], f1 = fl4[1];
  float fa[8] = {a0.x, a0.y, a0.z, a0.w, a1.x, a1.y, a1.z, a1.w};
  float fb[8] = {b0.x, b0.y, b0.z, b0.w, b1.x, b1.y, b1.z, b1.w};
  float ff[8] = {f0.x, f0.y, f0.z, f0.w, f1.x, f1.y, f1.z, f1.w};

  // ---- scan 1 (plain sum of e) -> d values in registers ----
  double lexcl[8];
  double run = 0.0;
#pragma unroll
  for (int r = 0; r < 8; ++r) {
    lexcl[r] = run;
    run += (double)fb[r] - (double)fa[r];
  }
  // intra-wave inclusive scan (Kogge-Stone, 64 lanes)
  double x = run;
#pragma unroll
  for (int off = 1; off < 64; off <<= 1) {
    double u = __shfl_up(x, off, 64);
    if (lane >= off) x += u;
  }
  if (lane == 63) wtot1[wid] = x;
  __syncthreads();
  double wexcl = 0.0;
  for (int w = 0; w < wid; ++w) wexcl += wtot1[w];  // 16 waves, fixed order
  const double texcl = wexcl + (x - run);           // thread-exclusive prefix of e

  double dv[8];
#pragma unroll
  for (int r = 0; r < 8; ++r) dv[r] = (double)ff[r] + texcl + lexcl[r];

  // ---- scan 2 (weighted): c_j = sum_{i<j} lam^{j-i} d_i ----
  // thread-local segment total: bl = applying 8 elems to c=0
  double bl = 0.0;
#pragma unroll
  for (int r = 0; r < 8; ++r) bl = LAM * (bl + dv[r]);

  const double m8 = pow((double)LAM, 8.0);
  // exclusive weighted scan across lanes: scan of bl shifted by one lane
  double y = __shfl_up(bl, 1, 64);
  if (lane < 1) y = 0.0;
  double xw = y;
  double m = m8;
#pragma unroll
  for (int off = 1; off < 64; off <<= 1) {
    double u = __shfl_up(xw, off, 64);
    if (lane >= off) xw += m * u;
    m *= m;
  }
  // xw = sum_{s<lane} m8^{lane-1-s} bl_s  (c entering this thread, wave-local)
  if (lane == 63) wtot2[wid] = bl + m8 * xw;  // wave inclusive weighted total
  __syncthreads();
  const double m512 = pow((double)LAM, 512.0);
  double Cw = 0.0;
  for (int w = 0; w < wid; ++w) Cw = m512 * Cw + wtot2[w];  // c entering this wave
  double c = pow(m8, (double)lane) * Cw + xw;               // c entering this thread

  // ---- weighted moments ----
  double t1 = 0.0, t2 = 0.0;
  double pj = pow((double)LAM, (double)base);         // lam^{idx}
  double qj = pow((double)LAM, (double)(TT - base));  // lam^{T-idx}
  const double invl = 1.0 / LAM;
#pragma unroll
  for (int r = 0; r < 8; ++r) {
    t1 += dv[r] * dv[r] * (2.0 - qj - pj);
    t2 += dv[r] * c;
    c = LAM * (c + dv[r]);
    pj *= LAM;
    qj *= invl;
  }
  if (tid == NTH - 1) {
    // idx = 8192: d_T = log_reward + full prefix; its c is this thread's final c
    const double dT = (double)log_reward[0] + (wexcl + x);
    const double pT = pow((double)LAM, (double)TT);  // ~0
    t1 += dT * dT * (2.0 - 1.0 - pT);                // lam^{T-T} = 1
    t2 += dT * c;
  }

  // ---- block reduction (fixed order, deterministic) ----
#pragma unroll
  for (int off = 32; off > 0; off >>= 1) {
    t1 += __shfl_down(t1, off, 64);
    t2 += __shfl_down(t2, off, 64);
  }
  if (lane == 0) { rt1[wid] = t1; rt2[wid] = t2; }
  __syncthreads();
  if (tid == 0) {
    double s1 = 0.0, s2 = 0.0;
    for (int w = 0; w < 16; ++w) { s1 += rt1[w]; s2 += rt2[w]; }
    const double total = (LAM / (1.0 - LAM)) * s1 - 2.0 * s2;
    out[0] = (float)(total / wsum);
  }
}

extern "C" void kernel_launch(void* const* d_in, const int* in_sizes, int n_in,
                              void* d_out, int out_size, void* d_ws, size_t ws_size,
                              hipStream_t stream) {
  const float* log_pfs    = (const float*)d_in[0];
  const float* log_pbs    = (const float*)d_in[1];
  const float* log_flows  = (const float*)d_in[2];
  const float* log_reward = (const float*)d_in[3];
  float* out = (float*)d_out;

  // exact wsum = sum_{k=1..T} (T+1-k) lam^k  (data-independent)
  double wsum = 0.0, lp = 1.0;
  for (int k = 1; k <= TT; ++k) {
    lp *= LAM;
    wsum += (double)(TT + 1 - k) * lp;
  }

  subtb_fused_kernel<<<1, NTH, 0, stream>>>(log_pfs, log_pbs, log_flows, log_reward, out, wsum);
}

// Round 3
// 10.710 us; speedup vs baseline: 1.8503x; 1.1728x over previous
//
#include <hip/hip_runtime.h>

// SubTB loss, T=8192, LAMBDA=0.9 — single fused kernel, O(T) exact.
// d_j = lfr_j + sum_{i<j} e_i,  e = log_pbs - log_pfs
// total = sum_{i<j} lam^{j-i} (d_i-d_j)^2
//       = [lam/(1-lam)] * sum_i d_i^2 (2 - lam^i - lam^{T-i})  -  2 * sum_j d_j c_j
//   where c_j = sum_{i<j} lam^{j-i} d_i  (linear recurrence c_{j+1} = lam*(c_j + d_j))
// wsum is data-independent, computed exactly on host.
// All lam powers are lam^(8n): binary exponentiation over a constexpr table
// (no runtime pow() libcalls — they were ~2/3 of the VALU work).

#define TT 8192
#define NTH 1024
#define LAM 0.9

constexpr double dpow(double b, long e) {
  double r = 1.0;
  for (long i = 0; i < e; ++i) r *= b;
  return r;
}

// M8P[b] = lam^(8 * 2^b), b = 0..10  (lam^8 .. lam^8192; last underflows to 0 — exact enough)
constexpr double M8P[11] = {
    dpow(LAM, 8L << 0), dpow(LAM, 8L << 1), dpow(LAM, 8L << 2), dpow(LAM, 8L << 3),
    dpow(LAM, 8L << 4), dpow(LAM, 8L << 5), dpow(LAM, 8L << 6), dpow(LAM, 8L << 7),
    dpow(LAM, 8L << 8), dpow(LAM, 8L << 9), dpow(LAM, 8L << 10)};

// lam^(8n) via bit-select multiplies (NB bits of n); compiles to cndmask+mul chain
template <int NB>
__device__ __forceinline__ double pow_m8(unsigned n) {
  double r = 1.0;
#pragma unroll
  for (int b = 0; b < NB; ++b) r *= ((n >> b) & 1u) ? M8P[b] : 1.0;
  return r;
}

__global__ __launch_bounds__(NTH) void subtb_fused_kernel(
    const float* __restrict__ log_pfs,
    const float* __restrict__ log_pbs,
    const float* __restrict__ log_flows,
    const float* __restrict__ log_reward,
    float* __restrict__ out, double wsum) {
  const int tid  = threadIdx.x;
  const int lane = tid & 63;
  const int wid  = tid >> 6;
  const int base = tid * 8;  // 1024 threads x 8 elems = 8192 (idx 8192 handled by last thread)

  __shared__ double wtot1[16];        // plain-scan wave totals
  __shared__ double wtot2[16];        // weighted-scan wave totals
  __shared__ double rt1[16], rt2[16]; // final reduction

  // ---- vectorized loads: 8 consecutive f32 per array ----
  const float4* pf4 = (const float4*)(log_pfs + base);
  const float4* pb4 = (const float4*)(log_pbs + base);
  const float4* fl4 = (const float4*)(log_flows + base);
  float4 a0 = pf4[0], a1 = pf4[1];
  float4 b0 = pb4[0], b1 = pb4[1];
  float4 f0 = fl4[0], f1 = fl4[1];
  float fa[8] = {a0.x, a0.y, a0.z, a0.w, a1.x, a1.y, a1.z, a1.w};
  float fb[8] = {b0.x, b0.y, b0.z, b0.w, b1.x, b1.y, b1.z, b1.w};
  float ff[8] = {f0.x, f0.y, f0.z, f0.w, f1.x, f1.y, f1.z, f1.w};

  // ---- scan 1 (plain sum of e) -> d values in registers ----
  double lexcl[8];
  double run = 0.0;
#pragma unroll
  for (int r = 0; r < 8; ++r) {
    lexcl[r] = run;
    run += (double)fb[r] - (double)fa[r];
  }
  // intra-wave inclusive scan (Kogge-Stone, 64 lanes)
  double x = run;
#pragma unroll
  for (int off = 1; off < 64; off <<= 1) {
    double u = __shfl_up(x, off, 64);
    if (lane >= off) x += u;
  }
  if (lane == 63) wtot1[wid] = x;
  __syncthreads();
  double wexcl = 0.0;
  for (int w = 0; w < wid; ++w) wexcl += wtot1[w];  // 16 waves, fixed order
  const double texcl = wexcl + (x - run);           // thread-exclusive prefix of e

  double dv[8];
#pragma unroll
  for (int r = 0; r < 8; ++r) dv[r] = (double)ff[r] + texcl + lexcl[r];

  // ---- scan 2 (weighted): c_j = sum_{i<j} lam^{j-i} d_i ----
  // thread-local segment total: bl = applying 8 elems to c=0
  double bl = 0.0;
#pragma unroll
  for (int r = 0; r < 8; ++r) bl = LAM * (bl + dv[r]);

  // exclusive weighted scan across lanes (weights = M8P[b] = m8^(2^b), no serial m*=m)
  double xw = __shfl_up(bl, 1, 64);
  if (lane < 1) xw = 0.0;
#pragma unroll
  for (int b = 0; b < 6; ++b) {
    const int off = 1 << b;
    double u = __shfl_up(xw, off, 64);
    if (lane >= off) xw += M8P[b] * u;
  }
  // xw = c entering this thread (wave-local)
  if (lane == 63) wtot2[wid] = bl + M8P[0] * xw;  // wave inclusive weighted total
  __syncthreads();
  double Cw = 0.0;
  for (int w = 0; w < wid; ++w) Cw = M8P[6] * Cw + wtot2[w];  // lam^512 per wave
  double c = pow_m8<6>((unsigned)lane) * Cw + xw;             // c entering this thread

  // ---- weighted moments ----
  double t1 = 0.0, t2 = 0.0;
  double pj = pow_m8<11>((unsigned)tid);          // lam^{base}
  double qj = pow_m8<11>((unsigned)(1024 - tid)); // lam^{TT-base}
  const double invl = 1.0 / LAM;
#pragma unroll
  for (int r = 0; r < 8; ++r) {
    t1 += dv[r] * dv[r] * (2.0 - qj - pj);
    t2 += dv[r] * c;
    c = LAM * (c + dv[r]);
    pj *= LAM;
    qj *= invl;
  }
  if (tid == NTH - 1) {
    // idx = 8192: d_T = log_reward + full prefix; its c is this thread's final c
    const double dT = (double)log_reward[0] + (wexcl + x);
    t1 += dT * dT;  // (2 - lam^{T-T} - lam^T) = (2 - 1 - 0) = 1
    t2 += dT * c;
  }

  // ---- block reduction (fixed order, deterministic) ----
#pragma unroll
  for (int off = 32; off > 0; off >>= 1) {
    t1 += __shfl_down(t1, off, 64);
    t2 += __shfl_down(t2, off, 64);
  }
  if (lane == 0) { rt1[wid] = t1; rt2[wid] = t2; }
  __syncthreads();
  if (tid == 0) {
    double s1 = 0.0, s2 = 0.0;
    for (int w = 0; w < 16; ++w) { s1 += rt1[w]; s2 += rt2[w]; }
    const double total = (LAM / (1.0 - LAM)) * s1 - 2.0 * s2;
    out[0] = (float)(total / wsum);
  }
}

extern "C" void kernel_launch(void* const* d_in, const int* in_sizes, int n_in,
                              void* d_out, int out_size, void* d_ws, size_t ws_size,
                              hipStream_t stream) {
  const float* log_pfs    = (const float*)d_in[0];
  const float* log_pbs    = (const float*)d_in[1];
  const float* log_flows  = (const float*)d_in[2];
  const float* log_reward = (const float*)d_in[3];
  float* out = (float*)d_out;

  // exact wsum = sum_{k=1..T} (T+1-k) lam^k  (data-independent; host, not timed)
  double wsum = 0.0, lp = 1.0;
  for (int k = 1; k <= TT; ++k) {
    lp *= LAM;
    wsum += (double)(TT + 1 - k) * lp;
  }

  subtb_fused_kernel<<<1, NTH, 0, stream>>>(log_pfs, log_pbs, log_flows, log_reward, out, wsum);
}

// Round 5
// 9.949 us; speedup vs baseline: 1.9917x; 1.0764x over previous
//
#include <hip/hip_runtime.h>

// SubTB loss, T=8192, LAMBDA=0.9 — single fused kernel, O(T) exact (no lambda truncation).
// d_j = lfr_j + sum_{i<j} e_i,  e = log_pbs - log_pfs
// total = sum_{i<j} lam^{j-i} (d_i-d_j)^2
//       = [lam/(1-lam)] * sum_i d_i^2 (2 - lam^i - lam^{T-i})  -  2 * sum_j d_j c_j
//   where c_j = sum_{i<j} lam^{j-i} d_i  (linear recurrence c_{j+1} = lam*(c_j + d_j))
// wsum data-independent, exact on host.
// Precision plan: f64 for the e-cumsum (accuracy anchor) and final 16-way sums;
// f32 for scan2/moments/reduction (error budget ~1e-3 << 0.43 threshold).
// f32 shuffles are 1 ds_bpermute vs 2 for f64; lam powers via v_exp_f32
// (__builtin_amdgcn_exp2f — NOT __exp2f, which doesn't compile under hipcc).

#define TT 8192
#define NTH 1024
#define LAM 0.9
#define LOG2LAM_F (-0.15200309344504995f)

constexpr double dpow(double b, long e) {
  double r = 1.0;
  for (long i = 0; i < e; ++i) r *= b;
  return r;
}

// M8F[b] = lam^(8 * 2^b), b = 0..6  (lam^8 .. lam^512), as f32
constexpr float M8F[7] = {
    (float)dpow(LAM, 8),   (float)dpow(LAM, 16),  (float)dpow(LAM, 32),
    (float)dpow(LAM, 64),  (float)dpow(LAM, 128), (float)dpow(LAM, 256),
    (float)dpow(LAM, 512)};

__global__ __launch_bounds__(NTH) void subtb_fused_kernel(
    const float* __restrict__ log_pfs,
    const float* __restrict__ log_pbs,
    const float* __restrict__ log_flows,
    const float* __restrict__ log_reward,
    float* __restrict__ out, double wsum) {
  const int tid  = threadIdx.x;
  const int lane = tid & 63;
  const int wid  = tid >> 6;
  const int base = tid * 8;  // 1024 threads x 8 elems = 8192 (idx 8192 handled by last thread)

  __shared__ double wtot1[16];       // plain-scan wave totals (f64)
  __shared__ float  wtot2[16];       // weighted-scan wave totals (f32)
  __shared__ float  rt1[16], rt2[16];

  // ---- vectorized loads ----
  const float4* pf4 = (const float4*)(log_pfs + base);
  const float4* pb4 = (const float4*)(log_pbs + base);
  const float4* fl4 = (const float4*)(log_flows + base);
  float4 a0 = pf4[0], a1 = pf4[1];
  float4 b0 = pb4[0], b1 = pb4[1];
  float4 f0 = fl4[0], f1 = fl4[1];
  float fa[8] = {a0.x, a0.y, a0.z, a0.w, a1.x, a1.y, a1.z, a1.w};
  float fb[8] = {b0.x, b0.y, b0.z, b0.w, b1.x, b1.y, b1.z, b1.w};
  float ff[8] = {f0.x, f0.y, f0.z, f0.w, f1.x, f1.y, f1.z, f1.w};

  // ---- scan 1 (plain sum of e), f64 ----
  double lexcl[8];
  double run = 0.0;
#pragma unroll
  for (int r = 0; r < 8; ++r) {
    lexcl[r] = run;
    run += (double)fb[r] - (double)fa[r];
  }
  double x = run;
#pragma unroll
  for (int off = 1; off < 64; off <<= 1) {
    double u = __shfl_up(x, off, 64);
    if (lane >= off) x += u;
  }
  if (lane == 63) wtot1[wid] = x;
  __syncthreads();
  double wexcl = 0.0;
  for (int w = 0; w < wid; ++w) wexcl += wtot1[w];  // fixed order
  const double texcl = wexcl + (x - run);

  float dvf[8];
#pragma unroll
  for (int r = 0; r < 8; ++r) dvf[r] = (float)((double)ff[r] + texcl + lexcl[r]);

  // ---- scan 2 (weighted, f32): c_j = sum_{i<j} lam^{j-i} d_i ----
  float bl = 0.0f;
#pragma unroll
  for (int r = 0; r < 8; ++r) bl = 0.9f * (bl + dvf[r]);

  float xw = __shfl_up(bl, 1, 64);
  if (lane < 1) xw = 0.0f;
#pragma unroll
  for (int b = 0; b < 6; ++b) {
    const int off = 1 << b;
    float u = __shfl_up(xw, off, 64);
    if (lane >= off) xw += M8F[b] * u;
  }
  if (lane == 63) wtot2[wid] = bl + M8F[0] * xw;
  __syncthreads();
  float Cw = 0.0f;
  for (int w = 0; w < wid; ++w) Cw = M8F[6] * Cw + wtot2[w];  // lam^512 per wave
  float c = __builtin_amdgcn_exp2f(8.0f * LOG2LAM_F * (float)lane) * Cw + xw;

  // ---- weighted moments (f32) ----
  float t1 = 0.0f, t2 = 0.0f;
  float pj = __builtin_amdgcn_exp2f(LOG2LAM_F * (float)base);         // lam^{base}
  float qj = __builtin_amdgcn_exp2f(LOG2LAM_F * (float)(TT - base));  // lam^{T-base} (~0 ok)
  const float invl = 1.0f / 0.9f;
#pragma unroll
  for (int r = 0; r < 8; ++r) {
    const float dr = dvf[r];
    t1 += dr * dr * (2.0f - qj - pj);
    t2 += dr * c;
    c = 0.9f * (c + dr);
    pj *= 0.9f;
    qj *= invl;
  }
  if (tid == NTH - 1) {
    // idx = 8192: d_T = log_reward + full prefix (f64 anchor); (2 - lam^0 - lam^T) = 1
    const double dT = (double)log_reward[0] + (wexcl + x);
    t1 += (float)(dT * dT);
    t2 += (float)dT * c;
  }

  // ---- block reduction (f32 shuffles, fixed order) ----
#pragma unroll
  for (int off = 32; off > 0; off >>= 1) {
    t1 += __shfl_down(t1, off, 64);
    t2 += __shfl_down(t2, off, 64);
  }
  if (lane == 0) { rt1[wid] = t1; rt2[wid] = t2; }
  __syncthreads();
  if (tid == 0) {
    double s1 = 0.0, s2 = 0.0;
    for (int w = 0; w < 16; ++w) { s1 += (double)rt1[w]; s2 += (double)rt2[w]; }
    const double total = (LAM / (1.0 - LAM)) * s1 - 2.0 * s2;
    out[0] = (float)(total / wsum);
  }
}

extern "C" void kernel_launch(void* const* d_in, const int* in_sizes, int n_in,
                              void* d_out, int out_size, void* d_ws, size_t ws_size,
                              hipStream_t stream) {
  const float* log_pfs    = (const float*)d_in[0];
  const float* log_pbs    = (const float*)d_in[1];
  const float* log_flows  = (const float*)d_in[2];
  const float* log_reward = (const float*)d_in[3];
  float* out = (float*)d_out;

  // exact wsum = sum_{k=1..T} (T+1-k) lam^k  (host, not timed)
  double wsum = 0.0, lp = 1.0;
  for (int k = 1; k <= TT; ++k) {
    lp *= LAM;
    wsum += (double)(TT + 1 - k) * lp;
  }

  subtb_fused_kernel<<<1, NTH, 0, stream>>>(log_pfs, log_pbs, log_flows, log_reward, out, wsum);
}

// Round 6
// 9.684 us; speedup vs baseline: 2.0462x; 1.0274x over previous
//
#include <hip/hip_runtime.h>

// SubTB loss, T=8192, LAMBDA=0.9 — single fused kernel, O(T) exact (no lambda truncation).
// e = log_pbs - log_pfs;  S_j = sum_{k<j} e_k;  d_j = lf_j + S_j (d_T = log_reward + S_T)
// total = [lam/(1-lam)] * sum_j d_j^2 (2 - lam^j - lam^{T-j})  -  2 * sum_j d_j c_j
// c_j = sum_{i<j} lam^{j-i} d_i  decomposes into THREE INDEPENDENT scans:
//   u_j = sum_{k<j} lam^{j-k} e_k   (weighted scan of e)
//   v_j = sum_{i<j} lam^{j-i} lf_i  (weighted scan of log_flows)
//   c_j = v_j + (lam/(1-lam)) S_j - (1/(1-lam)) u_j
// -> one Kogge-Stone phase with 3 interleaved independent shuffle chains,
//    ONE cross-wave barrier instead of two serial scan phases.
// wsum data-independent, exact on host. Final 16-partial combine in f64.

#define TT 8192
#define NTH 1024
#define LAMF 0.9f
#define INVLF (1.0f / 0.9f)
#define C1F 9.0f    // lam/(1-lam)
#define C2F 10.0f   // 1/(1-lam)
#define LOG2LAM_F (-0.15200309344504995f)

constexpr double dpow(double b, long e) {
  double r = 1.0;
  for (long i = 0; i < e; ++i) r *= b;
  return r;
}

// M8F[b] = lam^(8 * 2^b), b = 0..6  (lam^8 .. lam^512)
constexpr float M8F[7] = {
    (float)dpow(0.9, 8),   (float)dpow(0.9, 16),  (float)dpow(0.9, 32),
    (float)dpow(0.9, 64),  (float)dpow(0.9, 128), (float)dpow(0.9, 256),
    (float)dpow(0.9, 512)};

__global__ __launch_bounds__(NTH) void subtb_fused_kernel(
    const float* __restrict__ log_pfs,
    const float* __restrict__ log_pbs,
    const float* __restrict__ log_flows,
    const float* __restrict__ log_reward,
    float* __restrict__ out, double wsum) {
  const int tid  = threadIdx.x;
  const int lane = tid & 63;
  const int wid  = tid >> 6;
  const int base = tid * 8;  // 1024 threads x 8 elems = 8192 (idx 8192 by last thread)

  __shared__ float wS[16], wU[16], wV[16];  // wave totals: plain-e, weighted-e, weighted-lf
  __shared__ float rt1[16], rt2[16];

  // ---- vectorized loads ----
  const float4* pf4 = (const float4*)(log_pfs + base);
  const float4* pb4 = (const float4*)(log_pbs + base);
  const float4* fl4 = (const float4*)(log_flows + base);
  float4 a0 = pf4[0], a1 = pf4[1];
  float4 b0 = pb4[0], b1 = pb4[1];
  float4 f0 = fl4[0], f1 = fl4[1];
  float fe[8] = {b0.x - a0.x, b0.y - a0.y, b0.z - a0.z, b0.w - a0.w,
                 b1.x - a1.x, b1.y - a1.y, b1.z - a1.z, b1.w - a1.w};
  float ff[8] = {f0.x, f0.y, f0.z, f0.w, f1.x, f1.y, f1.z, f1.w};

  // ---- local segment folds (independent) ----
  float lexcl[8];
  float runS = 0.0f;  // plain sum of e
#pragma unroll
  for (int r = 0; r < 8; ++r) { lexcl[r] = runS; runS += fe[r]; }
  float blU = 0.0f;   // weighted fold of e
  float blV = 0.0f;   // weighted fold of lf
#pragma unroll
  for (int r = 0; r < 8; ++r) {
    blU = LAMF * (blU + fe[r]);
    blV = LAMF * (blV + ff[r]);
  }

  // ---- three interleaved Kogge-Stone chains across 64 lanes ----
  float xS = runS;                       // inclusive plain scan
  float xU = __shfl_up(blU, 1, 64);      // exclusive weighted scans
  float xV = __shfl_up(blV, 1, 64);
  if (lane == 0) { xU = 0.0f; xV = 0.0f; }
#pragma unroll
  for (int b = 0; b < 6; ++b) {
    const int off = 1 << b;
    float uS = __shfl_up(xS, off, 64);
    float uU = __shfl_up(xU, off, 64);
    float uV = __shfl_up(xV, off, 64);
    if (lane >= off) {
      xS += uS;
      xU += M8F[b] * uU;
      xV += M8F[b] * uV;
    }
  }
  if (lane == 63) {
    wS[wid] = xS;
    wU[wid] = blU + M8F[0] * xU;  // inclusive weighted wave totals
    wV[wid] = blV + M8F[0] * xV;
  }
  __syncthreads();

  // ---- cross-wave combine (fixed order, 15 iters max) ----
  float Sw = 0.0f, Uw = 0.0f, Vw = 0.0f;
  for (int w = 0; w < wid; ++w) {
    Sw += wS[w];
    Uw = M8F[6] * Uw + wU[w];  // lam^512 per wave
    Vw = M8F[6] * Vw + wV[w];
  }
  const float Sexcl = Sw + (xS - runS);                              // S at thread entry
  const float l8l = __builtin_amdgcn_exp2f(8.0f * LOG2LAM_F * (float)lane);  // lam^(8*lane)
  const float Uexcl = l8l * Uw + xU;                                 // u at thread entry
  const float Vexcl = l8l * Vw + xV;                                 // v at thread entry
  float c = Vexcl + C1F * Sexcl - C2F * Uexcl;                       // c at thread entry

  // ---- weighted moments ----
  float t1 = 0.0f, t2 = 0.0f;
  float pj = __builtin_amdgcn_exp2f(LOG2LAM_F * (float)base);        // lam^{j}
  float qj = __builtin_amdgcn_exp2f(LOG2LAM_F * (float)(TT - base)); // lam^{T-j} (~0 ok)
#pragma unroll
  for (int r = 0; r < 8; ++r) {
    const float d = ff[r] + Sexcl + lexcl[r];
    t1 += d * d * (2.0f - qj - pj);
    t2 += d * c;
    c = LAMF * (c + d);
    pj *= LAMF;
    qj *= INVLF;
  }
  if (tid == NTH - 1) {
    // j = T: d_T = log_reward + S_T; weight (2 - lam^T - lam^0) = 1
    const float dT = log_reward[0] + (Sw + xS);
    t1 += dT * dT;
    t2 += dT * c;
  }

  // ---- block reduction (fixed order, deterministic) ----
#pragma unroll
  for (int off = 32; off > 0; off >>= 1) {
    t1 += __shfl_down(t1, off, 64);
    t2 += __shfl_down(t2, off, 64);
  }
  if (lane == 0) { rt1[wid] = t1; rt2[wid] = t2; }
  __syncthreads();
  if (tid == 0) {
    double s1 = 0.0, s2 = 0.0;
    for (int w = 0; w < 16; ++w) { s1 += (double)rt1[w]; s2 += (double)rt2[w]; }
    const double total = 9.0 * s1 - 2.0 * s2;  // lam/(1-lam) = 9
    out[0] = (float)(total / wsum);
  }
}

extern "C" void kernel_launch(void* const* d_in, const int* in_sizes, int n_in,
                              void* d_out, int out_size, void* d_ws, size_t ws_size,
                              hipStream_t stream) {
  const float* log_pfs    = (const float*)d_in[0];
  const float* log_pbs    = (const float*)d_in[1];
  const float* log_flows  = (const float*)d_in[2];
  const float* log_reward = (const float*)d_in[3];
  float* out = (float*)d_out;

  // exact wsum = sum_{k=1..T} (T+1-k) lam^k  (host, not timed)
  double wsum = 0.0, lp = 1.0;
  for (int k = 1; k <= TT; ++k) {
    lp *= 0.9;
    wsum += (double)(TT + 1 - k) * lp;
  }

  subtb_fused_kernel<<<1, NTH, 0, stream>>>(log_pfs, log_pbs, log_flows, log_reward, out, wsum);
}